// Round 1
// baseline (2095.671 us; speedup 1.0000x reference)
//
#include <hip/hip_runtime.h>
#include <math.h>

// Model dims
#define D_MODEL 256
#define NTOK    8192      // B*S
#define SEQ     512
#define NB      16
#define NH      8
#define DHEAD   32
#define NE      8
#define EHID    1024

// ---------------------------------------------------------------------------
// Embedding + positional encoding + pad mask
// block per token (8192 blocks), 256 threads (one per feature dim)
// ---------------------------------------------------------------------------
__global__ __launch_bounds__(256) void embed_kernel(
    const int* __restrict__ x, const float* __restrict__ emb,
    float* __restrict__ h, int* __restrict__ pad)
{
    __shared__ float red[256];
    const int n = blockIdx.x;
    const int d = threadIdx.x;
    const int s = n & (SEQ - 1);
    const int tok = x[n];
    float v = emb[tok * D_MODEL + d] * 16.0f;   // sqrt(256)
    // positional encoding: pe[s,2j] = sin(s*div_j), pe[s,2j+1] = cos(s*div_j)
    const int j = d >> 1;
    const float c = -9.210340371976184f / 256.0f;    // -ln(10000)/256
    const float div = expf((float)(2 * j) * c);
    const float ang = (float)s * div;
    v += (d & 1) ? cosf(ang) : sinf(ang);
    h[n * D_MODEL + d] = v;
    // pad[n] = (sum_d h[n,d] == 0)
    red[d] = v;
    __syncthreads();
    for (int st = 128; st > 0; st >>= 1) {
        if (d < st) red[d] += red[d + st];
        __syncthreads();
    }
    if (d == 0) pad[n] = (red[0] == 0.0f) ? 1 : 0;
}

// ---------------------------------------------------------------------------
// Generic fp32 GEMM: C[M,N] = A[M,K] @ B[N,K]^T + bias[N]   (optional relu)
// 64x64 tile, BK=16, 256 threads, 4x4 per thread
// ---------------------------------------------------------------------------
__global__ __launch_bounds__(256) void gemm_bt(
    const float* __restrict__ A, const float* __restrict__ B,
    const float* __restrict__ bias, float* __restrict__ C,
    int M, int N, int K, int relu)
{
    __shared__ float As[16][64];
    __shared__ float Bs[16][64];
    const int tid = threadIdx.x;
    const int tx = tid & 15, ty = tid >> 4;
    const int m0 = blockIdx.y * 64, n0 = blockIdx.x * 64;
    const int lr = tid >> 2;           // 0..63
    const int lk = (tid & 3) << 2;     // 0,4,8,12
    const float* Aptr = A + (size_t)(m0 + lr) * K + lk;
    const float* Bptr = B + (size_t)(n0 + lr) * K + lk;
    float acc[4][4] = {};
    for (int k0 = 0; k0 < K; k0 += 16) {
        float4 av = *(const float4*)(Aptr + k0);
        float4 bv = *(const float4*)(Bptr + k0);
        As[lk + 0][lr] = av.x; As[lk + 1][lr] = av.y;
        As[lk + 2][lr] = av.z; As[lk + 3][lr] = av.w;
        Bs[lk + 0][lr] = bv.x; Bs[lk + 1][lr] = bv.y;
        Bs[lk + 2][lr] = bv.z; Bs[lk + 3][lr] = bv.w;
        __syncthreads();
#pragma unroll
        for (int kk = 0; kk < 16; kk++) {
            float4 a = *(const float4*)&As[kk][ty << 2];
            float4 b = *(const float4*)&Bs[kk][tx << 2];
            acc[0][0] += a.x * b.x; acc[0][1] += a.x * b.y; acc[0][2] += a.x * b.z; acc[0][3] += a.x * b.w;
            acc[1][0] += a.y * b.x; acc[1][1] += a.y * b.y; acc[1][2] += a.y * b.z; acc[1][3] += a.y * b.w;
            acc[2][0] += a.z * b.x; acc[2][1] += a.z * b.y; acc[2][2] += a.z * b.z; acc[2][3] += a.z * b.w;
            acc[3][0] += a.w * b.x; acc[3][1] += a.w * b.y; acc[3][2] += a.w * b.z; acc[3][3] += a.w * b.w;
        }
        __syncthreads();
    }
#pragma unroll
    for (int i = 0; i < 4; i++) {
        const int m = m0 + (ty << 2) + i;
#pragma unroll
        for (int jj = 0; jj < 4; jj++) {
            const int nn = n0 + (tx << 2) + jj;
            float v = acc[i][jj] + bias[nn];
            if (relu) v = fmaxf(v, 0.0f);
            C[(size_t)m * N + nn] = v;
        }
    }
}

// ---------------------------------------------------------------------------
// Attention: lane-per-query, single pass (no max-sub), K/V broadcast reads.
// grid = B*H*(S/64) = 1024 blocks of 128 threads (2 waves split the keys)
// qkv layout [n][768]: q 0..255, k 256..511, v 512..767
// ---------------------------------------------------------------------------
__global__ __launch_bounds__(128) void attn_kernel(
    const float* __restrict__ qkv, const int* __restrict__ pad,
    float* __restrict__ ctx)
{
    __shared__ float part[64][34];  // [lane][acc 0..31, l at 32]
    const int tid = threadIdx.x;
    const int lane = tid & 63;
    const int wave = tid >> 6;
    const int bid = blockIdx.x;
    const int qt = bid & 7;
    const int hh = (bid >> 3) & 7;
    const int b = bid >> 6;
    const int q = qt * 64 + lane;
    const int n = b * SEQ + q;

    float qv[32];
    const float* qrow = qkv + (size_t)n * 768 + hh * 32;
#pragma unroll
    for (int i = 0; i < 8; i++) {
        float4 t = *(const float4*)(qrow + i * 4);
        qv[i * 4 + 0] = t.x; qv[i * 4 + 1] = t.y; qv[i * 4 + 2] = t.z; qv[i * 4 + 3] = t.w;
    }
    const float scale = 0.17677669529663687f;  // 1/sqrt(32)
    float l = 0.0f;
    float acc[32] = {};
    const int k0 = wave * 256;
    const float* base = qkv + (size_t)(b * SEQ + k0) * 768;
    const int* padb = pad + b * SEQ + k0;
    for (int k = 0; k < 256; k++) {
        const float* krow = base + (size_t)k * 768 + 256 + hh * 32;
        float s0 = 0, s1 = 0, s2 = 0, s3 = 0;
#pragma unroll
        for (int i = 0; i < 8; i++) {
            float4 kv = *(const float4*)(krow + i * 4);
            s0 += qv[i * 4 + 0] * kv.x; s1 += qv[i * 4 + 1] * kv.y;
            s2 += qv[i * 4 + 2] * kv.z; s3 += qv[i * 4 + 3] * kv.w;
        }
        float s = ((s0 + s1) + (s2 + s3)) * scale;
        if (padb[k]) s = -1e9f;
        const float p = __expf(s);
        l += p;
        const float* vrow = krow + 256;
#pragma unroll
        for (int i = 0; i < 8; i++) {
            float4 vv = *(const float4*)(vrow + i * 4);
            acc[i * 4 + 0] += p * vv.x; acc[i * 4 + 1] += p * vv.y;
            acc[i * 4 + 2] += p * vv.z; acc[i * 4 + 3] += p * vv.w;
        }
    }
    if (wave == 1) {
#pragma unroll
        for (int i = 0; i < 32; i++) part[lane][i] = acc[i];
        part[lane][32] = l;
    }
    __syncthreads();
    if (wave == 0) {
        l += part[lane][32];
        const float inv = 1.0f / l;
        float* out = ctx + (size_t)n * D_MODEL + hh * 32;
#pragma unroll
        for (int i = 0; i < 32; i++) out[i] = (acc[i] + part[lane][i]) * inv;
    }
}

// ---------------------------------------------------------------------------
// Residual add + LayerNorm (in place into h). block per token, 256 threads.
// ---------------------------------------------------------------------------
__global__ __launch_bounds__(256) void add_ln(
    float* __restrict__ h, const float* __restrict__ add,
    const float* __restrict__ g, const float* __restrict__ b)
{
    __shared__ float red[256];
    const int n = blockIdx.x;
    const int d = threadIdx.x;
    const float v = h[n * D_MODEL + d] + add[n * D_MODEL + d];
    red[d] = v;
    __syncthreads();
    for (int st = 128; st > 0; st >>= 1) {
        if (d < st) red[d] += red[d + st];
        __syncthreads();
    }
    const float mu = red[0] * (1.0f / 256.0f);
    __syncthreads();
    const float c = v - mu;
    red[d] = c * c;
    __syncthreads();
    for (int st = 128; st > 0; st >>= 1) {
        if (d < st) red[d] += red[d + st];
        __syncthreads();
    }
    const float var = red[0] * (1.0f / 256.0f);
    h[n * D_MODEL + d] = c * rsqrtf(var + 1e-5f) * g[d] + b[d];
}

// ---------------------------------------------------------------------------
// Gate: logits -> softmax top-1 weight + argmax + bucket position (atomic)
// one wave per token
// ---------------------------------------------------------------------------
__global__ __launch_bounds__(64) void gate_kernel(
    const float* __restrict__ h, const float* __restrict__ gw,
    const float* __restrict__ gb, int* __restrict__ top_idx,
    float* __restrict__ top_w, int* __restrict__ pos, int* __restrict__ counts)
{
    const int n = blockIdx.x;
    const int lane = threadIdx.x;
    float part[NE] = {};
    for (int d = lane; d < D_MODEL; d += 64) {
        const float hv = h[n * D_MODEL + d];
#pragma unroll
        for (int e = 0; e < NE; e++) part[e] += hv * gw[e * D_MODEL + d];
    }
#pragma unroll
    for (int e = 0; e < NE; e++) {
        float v = part[e];
        for (int o = 32; o > 0; o >>= 1) v += __shfl_down(v, o, 64);
        part[e] = v;
    }
    if (lane == 0) {
        float lg[NE];
        float best = -1e30f; int bi = 0;
#pragma unroll
        for (int e = 0; e < NE; e++) {
            lg[e] = part[e] + gb[e];
            if (lg[e] > best) { best = lg[e]; bi = e; }   // first-max tie-break
        }
        float ssum = 0.0f;
#pragma unroll
        for (int e = 0; e < NE; e++) ssum += __expf(lg[e] - best);
        top_idx[n] = bi;
        top_w[n] = 1.0f / ssum;     // = softmax max prob
        pos[n] = atomicAdd(&counts[bi], 1);
    }
}

__global__ void offsets_kernel(const int* __restrict__ counts, int* __restrict__ offs)
{
    if (threadIdx.x == 0 && blockIdx.x == 0) {
        int a = 0;
        for (int e = 0; e < NE; e++) { offs[e] = a; a += counts[e]; }
    }
}

__global__ __launch_bounds__(256) void scatter_perm(
    const int* __restrict__ top_idx, const int* __restrict__ pos,
    const int* __restrict__ offs, int* __restrict__ perm)
{
    const int n = blockIdx.x * 256 + threadIdx.x;
    if (n < NTOK) perm[offs[top_idx[n]] + pos[n]] = n;
}

// ---------------------------------------------------------------------------
// MoE expert GEMM 1: eh[r, :] = relu(x[perm[r]] @ w1[e]^T + b1[e])
// grid (EHID/64, ceil(NTOK/64), NE); blocks past segment end exit early.
// ---------------------------------------------------------------------------
__global__ __launch_bounds__(256) void moe_fc1(
    const float* __restrict__ Xf, const float* __restrict__ w1l,
    const float* __restrict__ b1l, const int* __restrict__ perm,
    const int* __restrict__ counts, const int* __restrict__ offs,
    float* __restrict__ eh)
{
    __shared__ float As[16][64];
    __shared__ float Bs[16][64];
    const int e = blockIdx.z;
    const int cnt = counts[e];
    const int m0 = blockIdx.y * 64;
    if (m0 >= cnt) return;
    const int off = offs[e];
    const int n0 = blockIdx.x * 64;
    const float* B = w1l + (size_t)e * EHID * D_MODEL;
    const int tid = threadIdx.x;
    const int tx = tid & 15, ty = tid >> 4;
    const int lr = tid >> 2;
    const int lk = (tid & 3) << 2;
    const int rrow = m0 + lr;
    const bool rvalid = rrow < cnt;
    const int tok = rvalid ? perm[off + rrow] : 0;
    const float* Aptr = Xf + (size_t)tok * D_MODEL + lk;
    const float* Bptr = B + (size_t)(n0 + lr) * D_MODEL + lk;
    float acc[4][4] = {};
    for (int k0 = 0; k0 < D_MODEL; k0 += 16) {
        float4 av = rvalid ? *(const float4*)(Aptr + k0) : make_float4(0, 0, 0, 0);
        float4 bv = *(const float4*)(Bptr + k0);
        As[lk + 0][lr] = av.x; As[lk + 1][lr] = av.y;
        As[lk + 2][lr] = av.z; As[lk + 3][lr] = av.w;
        Bs[lk + 0][lr] = bv.x; Bs[lk + 1][lr] = bv.y;
        Bs[lk + 2][lr] = bv.z; Bs[lk + 3][lr] = bv.w;
        __syncthreads();
#pragma unroll
        for (int kk = 0; kk < 16; kk++) {
            float4 a = *(const float4*)&As[kk][ty << 2];
            float4 b = *(const float4*)&Bs[kk][tx << 2];
            acc[0][0] += a.x * b.x; acc[0][1] += a.x * b.y; acc[0][2] += a.x * b.z; acc[0][3] += a.x * b.w;
            acc[1][0] += a.y * b.x; acc[1][1] += a.y * b.y; acc[1][2] += a.y * b.z; acc[1][3] += a.y * b.w;
            acc[2][0] += a.z * b.x; acc[2][1] += a.z * b.y; acc[2][2] += a.z * b.z; acc[2][3] += a.z * b.w;
            acc[3][0] += a.w * b.x; acc[3][1] += a.w * b.y; acc[3][2] += a.w * b.z; acc[3][3] += a.w * b.w;
        }
        __syncthreads();
    }
#pragma unroll
    for (int i = 0; i < 4; i++) {
        const int m = m0 + (ty << 2) + i;
        if (m < cnt) {
#pragma unroll
            for (int jj = 0; jj < 4; jj++) {
                const int nn = n0 + (tx << 2) + jj;
                const float v = acc[i][jj] + b1l[e * EHID + nn];
                eh[(size_t)(off + m) * EHID + nn] = fmaxf(v, 0.0f);
            }
        }
    }
}

// ---------------------------------------------------------------------------
// MoE expert GEMM 2: moe[tok, :] = top_w[tok] * (eh[r,:] @ w2[e]^T + b2[e])
// grid (D/64, ceil(NTOK/64), NE)
// ---------------------------------------------------------------------------
__global__ __launch_bounds__(256) void moe_fc2(
    const float* __restrict__ eh, const float* __restrict__ w2l,
    const float* __restrict__ b2l, const int* __restrict__ perm,
    const int* __restrict__ counts, const int* __restrict__ offs,
    const float* __restrict__ top_w, float* __restrict__ moe)
{
    __shared__ float As[16][64];
    __shared__ float Bs[16][64];
    const int e = blockIdx.z;
    const int cnt = counts[e];
    const int m0 = blockIdx.y * 64;
    if (m0 >= cnt) return;
    const int off = offs[e];
    const int n0 = blockIdx.x * 64;
    const float* B = w2l + (size_t)e * D_MODEL * EHID;
    const int tid = threadIdx.x;
    const int tx = tid & 15, ty = tid >> 4;
    const int lr = tid >> 2;
    const int lk = (tid & 3) << 2;
    const int rrow = m0 + lr;
    const bool rvalid = rrow < cnt;
    const float* Aptr = eh + (size_t)(off + (rvalid ? rrow : 0)) * EHID + lk;
    const float* Bptr = B + (size_t)(n0 + lr) * EHID + lk;
    float acc[4][4] = {};
    for (int k0 = 0; k0 < EHID; k0 += 16) {
        float4 av = rvalid ? *(const float4*)(Aptr + k0) : make_float4(0, 0, 0, 0);
        float4 bv = *(const float4*)(Bptr + k0);
        As[lk + 0][lr] = av.x; As[lk + 1][lr] = av.y;
        As[lk + 2][lr] = av.z; As[lk + 3][lr] = av.w;
        Bs[lk + 0][lr] = bv.x; Bs[lk + 1][lr] = bv.y;
        Bs[lk + 2][lr] = bv.z; Bs[lk + 3][lr] = bv.w;
        __syncthreads();
#pragma unroll
        for (int kk = 0; kk < 16; kk++) {
            float4 a = *(const float4*)&As[kk][ty << 2];
            float4 b = *(const float4*)&Bs[kk][tx << 2];
            acc[0][0] += a.x * b.x; acc[0][1] += a.x * b.y; acc[0][2] += a.x * b.z; acc[0][3] += a.x * b.w;
            acc[1][0] += a.y * b.x; acc[1][1] += a.y * b.y; acc[1][2] += a.y * b.z; acc[1][3] += a.y * b.w;
            acc[2][0] += a.z * b.x; acc[2][1] += a.z * b.y; acc[2][2] += a.z * b.z; acc[2][3] += a.z * b.w;
            acc[3][0] += a.w * b.x; acc[3][1] += a.w * b.y; acc[3][2] += a.w * b.z; acc[3][3] += a.w * b.w;
        }
        __syncthreads();
    }
#pragma unroll
    for (int i = 0; i < 4; i++) {
        const int m = m0 + (ty << 2) + i;
        if (m < cnt) {
            const int tokm = perm[off + m];
            const float sc = top_w[tokm];
#pragma unroll
            for (int jj = 0; jj < 4; jj++) {
                const int nn = n0 + (tx << 2) + jj;
                moe[(size_t)tokm * D_MODEL + nn] = (acc[i][jj] + b2l[e * D_MODEL + nn]) * sc;
            }
        }
    }
}

// ---------------------------------------------------------------------------
// Masked mean pool over sequence. block per batch, thread per dim.
// ---------------------------------------------------------------------------
__global__ __launch_bounds__(256) void pool_kernel(
    const float* __restrict__ h, const int* __restrict__ pad,
    float* __restrict__ pooled)
{
    const int b = blockIdx.x;
    const int d = threadIdx.x;
    float s = 0.0f, cnt = 0.0f;
    for (int i = 0; i < SEQ; i++) {
        if (!pad[b * SEQ + i]) {
            s += h[(size_t)(b * SEQ + i) * D_MODEL + d];
            cnt += 1.0f;
        }
    }
    pooled[b * D_MODEL + d] = s / fmaxf(cnt, 1.0f);
}

// ---------------------------------------------------------------------------
// Classifier head: out = relu(pooled @ fc1^T + b) @ fc2^T + b
// ---------------------------------------------------------------------------
__global__ __launch_bounds__(128) void cls_kernel(
    const float* __restrict__ pooled, const float* __restrict__ fc1w,
    const float* __restrict__ fc1b, const float* __restrict__ fc2w,
    const float* __restrict__ fc2b, float* __restrict__ out)
{
    __shared__ float zs[128];
    const int b = blockIdx.x;
    const int j = threadIdx.x;
    float s = fc1b[j];
    for (int d = 0; d < D_MODEL; d++) s += pooled[b * D_MODEL + d] * fc1w[j * D_MODEL + d];
    zs[j] = fmaxf(s, 0.0f);
    __syncthreads();
    if (j < 2) {
        float o = fc2b[j];
        for (int i = 0; i < 128; i++) o += zs[i] * fc2w[j * 128 + i];
        out[b * 2 + j] = o;
    }
}

// ---------------------------------------------------------------------------
extern "C" void kernel_launch(void* const* d_in, const int* in_sizes, int n_in,
                              void* d_out, int out_size, void* d_ws, size_t ws_size,
                              hipStream_t stream)
{
    const int*   x          = (const int*)d_in[0];
    const float* emb        = (const float*)d_in[1];
    const float* in_proj_w  = (const float*)d_in[2];
    const float* in_proj_b  = (const float*)d_in[3];
    const float* out_proj_w = (const float*)d_in[4];
    const float* out_proj_b = (const float*)d_in[5];
    const float* ln1_g      = (const float*)d_in[6];
    const float* ln1_b      = (const float*)d_in[7];
    const float* ln2_g      = (const float*)d_in[8];
    const float* ln2_b      = (const float*)d_in[9];
    const float* gate_w     = (const float*)d_in[10];
    const float* gate_b     = (const float*)d_in[11];
    const float* w1         = (const float*)d_in[12];
    const float* b1         = (const float*)d_in[13];
    const float* w2         = (const float*)d_in[14];
    const float* b2         = (const float*)d_in[15];
    const float* fc1_w      = (const float*)d_in[16];
    const float* fc1_b      = (const float*)d_in[17];
    const float* fc2_w      = (const float*)d_in[18];
    const float* fc2_b      = (const float*)d_in[19];
    float* out = (float*)d_out;

    // workspace layout (floats)
    float* ws = (float*)d_ws;
    float* h     = ws;                 // 8192*256   = 2,097,152
    float* tmp   = ws + 2097152;       // 8192*256   (attn_out, then moe_out)
    float* qkv   = ws + 4194304;       // 8192*768   = 6,291,456
    float* ctx   = ws + 10485760;      // 8192*256
    float* eh    = ws + 4194304;       // 8192*1024 aliases qkv+ctx (dead by then)
    float* top_w = ws + 12582912;      // 8192
    float* pooled = ws + 12591104;     // 16*256
    int* ipart   = (int*)(ws + 12595200);
    int* pad     = ipart;              // 8192
    int* top_idx = ipart + 8192;
    int* pos     = ipart + 16384;
    int* perm    = ipart + 24576;
    int* counts  = ipart + 32768;      // 8
    int* offs    = ipart + 32776;      // 8

    embed_kernel<<<NTOK, 256, 0, stream>>>(x, emb, h, pad);

    for (int l = 0; l < 2; l++) {
        // qkv projection: [8192,256] x [768,256]^T
        gemm_bt<<<dim3(768 / 64, NTOK / 64), 256, 0, stream>>>(
            h, in_proj_w + (size_t)l * 768 * 256, in_proj_b + l * 768,
            qkv, NTOK, 768, 256, 0);
        // attention
        attn_kernel<<<NB * NH * (SEQ / 64), 128, 0, stream>>>(qkv, pad, ctx);
        // output projection
        gemm_bt<<<dim3(256 / 64, NTOK / 64), 256, 0, stream>>>(
            ctx, out_proj_w + (size_t)l * 256 * 256, out_proj_b + l * 256,
            tmp, NTOK, 256, 256, 0);
        add_ln<<<NTOK, 256, 0, stream>>>(h, tmp, ln1_g + l * 256, ln1_b + l * 256);
        // MoE routing
        hipMemsetAsync(counts, 0, NE * sizeof(int), stream);
        gate_kernel<<<NTOK, 64, 0, stream>>>(
            h, gate_w + l * NE * 256, gate_b + l * NE, top_idx, top_w, pos, counts);
        offsets_kernel<<<1, 1, 0, stream>>>(counts, offs);
        scatter_perm<<<NTOK / 256, 256, 0, stream>>>(top_idx, pos, offs, perm);
        // MoE expert GEMMs (only routed expert per token)
        moe_fc1<<<dim3(EHID / 64, NTOK / 64, NE), 256, 0, stream>>>(
            h, w1 + (size_t)l * NE * EHID * 256, b1 + l * NE * EHID,
            perm, counts, offs, eh);
        moe_fc2<<<dim3(D_MODEL / 64, NTOK / 64, NE), 256, 0, stream>>>(
            eh, w2 + (size_t)l * NE * 256 * EHID, b2 + l * NE * 256,
            perm, counts, offs, top_w, tmp);
        add_ln<<<NTOK, 256, 0, stream>>>(h, tmp, ln2_g + l * 256, ln2_b + l * 256);
    }

    pool_kernel<<<NB, 256, 0, stream>>>(h, pad, pooled);
    cls_kernel<<<NB, 128, 0, stream>>>(pooled, fc1_w, fc1_b, fc2_w, fc2_b, out);
}

// Round 2
// 880.818 us; speedup vs baseline: 2.3792x; 2.3792x over previous
//
#include <hip/hip_runtime.h>
#include <math.h>

// Model dims
#define D_MODEL 256
#define NTOK    8192      // B*S
#define SEQ     512
#define NB      16
#define NH      8
#define DHEAD   32
#define NE      8
#define EHID    1024

typedef __attribute__((ext_vector_type(8))) short short8;
typedef __attribute__((ext_vector_type(4))) float floatx4;
typedef unsigned short ushort_t;

__device__ __forceinline__ ushort_t bf16r(float f) {
    unsigned int u = __float_as_uint(f);
    u += 0x7fffu + ((u >> 16) & 1u);     // round-to-nearest-even
    return (ushort_t)(u >> 16);
}
__device__ __forceinline__ void cvt8(uint4 u, float* f) {
    f[0] = __uint_as_float(u.x << 16); f[1] = __uint_as_float(u.x & 0xffff0000u);
    f[2] = __uint_as_float(u.y << 16); f[3] = __uint_as_float(u.y & 0xffff0000u);
    f[4] = __uint_as_float(u.z << 16); f[5] = __uint_as_float(u.z & 0xffff0000u);
    f[6] = __uint_as_float(u.w << 16); f[7] = __uint_as_float(u.w & 0xffff0000u);
}

// ---------------------------------------------------------------------------
// fp32 -> bf16 conversion (weights)
// ---------------------------------------------------------------------------
__global__ __launch_bounds__(256) void wconv(
    const float* __restrict__ src, ushort_t* __restrict__ dst, int n)
{
    const int i = (blockIdx.x * 256 + threadIdx.x) * 4;
    if (i < n) {
        float4 v = *(const float4*)(src + i);
        ushort_t o[4] = { bf16r(v.x), bf16r(v.y), bf16r(v.z), bf16r(v.w) };
        *(uint2*)(dst + i) = *(uint2*)o;
    }
}

// ---------------------------------------------------------------------------
// Embedding + positional encoding + pad mask. Writes h (fp32) and hb (bf16).
// ---------------------------------------------------------------------------
__global__ __launch_bounds__(256) void embed_kernel(
    const int* __restrict__ x, const float* __restrict__ emb,
    float* __restrict__ h, ushort_t* __restrict__ hb, int* __restrict__ pad)
{
    __shared__ float red[256];
    const int n = blockIdx.x;
    const int d = threadIdx.x;
    const int s = n & (SEQ - 1);
    const int tok = x[n];
    float v = emb[tok * D_MODEL + d] * 16.0f;   // sqrt(256)
    const int j = d >> 1;
    const float c = -9.210340371976184f / 256.0f;    // -ln(10000)/256
    const float div = expf((float)(2 * j) * c);
    const float ang = (float)s * div;
    v += (d & 1) ? cosf(ang) : sinf(ang);
    h[n * D_MODEL + d] = v;
    hb[n * D_MODEL + d] = bf16r(v);
    red[d] = v;
    __syncthreads();
    for (int st = 128; st > 0; st >>= 1) {
        if (d < st) red[d] += red[d + st];
        __syncthreads();
    }
    if (d == 0) pad[n] = (red[0] == 0.0f) ? 1 : 0;
}

// ---------------------------------------------------------------------------
// Generic bf16 MFMA GEMM: C[M,N] = A[M,K] @ B[N,K]^T + bias[N]
// 64x64 tile, BK=64, 256 threads (4 waves, 2x2), mfma_f32_16x16x32_bf16.
// Flags select gather-A (MoE fc1), relu, bf16 output, scatter+scale output
// (MoE fc2). Segmented mode when counts != nullptr (blockIdx.z = expert).
// ---------------------------------------------------------------------------
#define GF_RELU    1
#define GF_OUTBF16 2
#define GF_GATHER  4
#define GF_SCATTER 8

__global__ __launch_bounds__(256) void mfma_gemm(
    const ushort_t* __restrict__ A, const ushort_t* __restrict__ Bw,
    const float* __restrict__ bias, void* __restrict__ Cout,
    int M, int N, int K,
    const int* __restrict__ counts, const int* __restrict__ offs,
    const int* __restrict__ perm, const float* __restrict__ topw,
    int flags)
{
    __shared__ ushort_t As[64][72];   // 64 rows x (64 + 8 pad) bf16
    __shared__ ushort_t Bs[64][72];
    const int e = blockIdx.z;
    int cnt, off;
    if (counts) {
        cnt = counts[e]; off = offs[e];
        if ((int)blockIdx.y * 64 >= cnt) return;
    } else { cnt = M; off = 0; }
    const ushort_t* Bp = Bw + (size_t)e * N * K;
    const float* bp = bias + (size_t)e * N;
    const int m0 = blockIdx.y * 64, n0 = blockIdx.x * 64;
    const int tid = threadIdx.x;
    // staging: thread handles rows (tid>>3) and (tid>>3)+32, k-chunk (tid&7)*8
    const int sr0 = tid >> 3;          // 0..31
    const int kc0 = (tid & 7) * 8;     // 0..56
    const int r0 = m0 + sr0, r1 = r0 + 32;
    const bool v0 = r0 < cnt, v1 = r1 < cnt;
    size_t a0, a1;
    if (flags & GF_GATHER) {
        a0 = (size_t)perm[off + (v0 ? r0 : 0)];
        a1 = (size_t)perm[off + (v1 ? r1 : 0)];
    } else {
        a0 = (size_t)(off + (v0 ? r0 : 0));
        a1 = (size_t)(off + (v1 ? r1 : 0));
    }
    const ushort_t* Ap0 = A + a0 * K + kc0;
    const ushort_t* Ap1 = A + a1 * K + kc0;
    const ushort_t* Bp0 = Bp + (size_t)(n0 + sr0) * K + kc0;
    const ushort_t* Bp1 = Bp + (size_t)(n0 + sr0 + 32) * K + kc0;
    // wave / fragment indices
    const int lane = tid & 63, wave = tid >> 6;
    const int wm = (wave & 1) * 32, wn = (wave >> 1) * 32;
    const int fr = lane & 15, fk = (lane >> 4) * 8;
    floatx4 acc[2][2];
#pragma unroll
    for (int i = 0; i < 2; i++)
#pragma unroll
        for (int jj = 0; jj < 2; jj++) acc[i][jj] = (floatx4){0.f, 0.f, 0.f, 0.f};

    for (int k0 = 0; k0 < K; k0 += 64) {
        uint4 av0 = *(const uint4*)(Ap0 + k0);
        uint4 av1 = *(const uint4*)(Ap1 + k0);
        uint4 bv0 = *(const uint4*)(Bp0 + k0);
        uint4 bv1 = *(const uint4*)(Bp1 + k0);
        __syncthreads();
        *(uint4*)&As[sr0][kc0]      = av0;
        *(uint4*)&As[sr0 + 32][kc0] = av1;
        *(uint4*)&Bs[sr0][kc0]      = bv0;
        *(uint4*)&Bs[sr0 + 32][kc0] = bv1;
        __syncthreads();
#pragma unroll
        for (int ks = 0; ks < 2; ks++) {
            const int ko = ks * 32 + fk;
            short8 fa0 = *(const short8*)&As[wm + fr][ko];
            short8 fa1 = *(const short8*)&As[wm + 16 + fr][ko];
            short8 fb0 = *(const short8*)&Bs[wn + fr][ko];
            short8 fb1 = *(const short8*)&Bs[wn + 16 + fr][ko];
            acc[0][0] = __builtin_amdgcn_mfma_f32_16x16x32_bf16(fa0, fb0, acc[0][0], 0, 0, 0);
            acc[0][1] = __builtin_amdgcn_mfma_f32_16x16x32_bf16(fa0, fb1, acc[0][1], 0, 0, 0);
            acc[1][0] = __builtin_amdgcn_mfma_f32_16x16x32_bf16(fa1, fb0, acc[1][0], 0, 0, 0);
            acc[1][1] = __builtin_amdgcn_mfma_f32_16x16x32_bf16(fa1, fb1, acc[1][1], 0, 0, 0);
        }
    }
    // epilogue: C/D layout col=lane&15, row=(lane>>4)*4+reg
    const int crow0 = (lane >> 4) * 4;
    const int ccol = lane & 15;
#pragma unroll
    for (int fm = 0; fm < 2; fm++) {
#pragma unroll
        for (int fn = 0; fn < 2; fn++) {
            const int gcol = n0 + wn + fn * 16 + ccol;
            const float bsv = bp[gcol];
#pragma unroll
            for (int r = 0; r < 4; r++) {
                const int grow = m0 + wm + fm * 16 + crow0 + r;
                if (grow >= cnt) continue;
                float v = acc[fm][fn][r] + bsv;
                if (flags & GF_RELU) v = fmaxf(v, 0.f);
                if (flags & GF_SCATTER) {
                    const int tok = perm[off + grow];
                    ((float*)Cout)[(size_t)tok * N + gcol] = v * topw[tok];
                } else if (flags & GF_OUTBF16) {
                    ((ushort_t*)Cout)[(size_t)(off + grow) * N + gcol] = bf16r(v);
                } else {
                    ((float*)Cout)[(size_t)(off + grow) * N + gcol] = v;
                }
            }
        }
    }
}

// ---------------------------------------------------------------------------
// Attention: 64 queries/block (one per lane), 4 waves split keys.
// K/V staged per 128-key tile into LDS as fp32 (converted once, shared by all
// lanes). fp32 accumulate; bf16 in (qkvb), bf16 out (ctxb).
// grid = B*H*(S/64) = 1024 blocks x 256 threads.
// ---------------------------------------------------------------------------
__global__ __launch_bounds__(256) void attn_kernel(
    const ushort_t* __restrict__ qkvb, const int* __restrict__ pad,
    ushort_t* __restrict__ ctxb)
{
    __shared__ float smem[8320];   // K: 0..4095, V: 4096..8191, pad: 8192..8319
    const int tid = threadIdx.x;
    const int lane = tid & 63;
    const int wave = tid >> 6;
    const int bid = blockIdx.x;
    const int qt = bid & 7;
    const int hh = (bid >> 3) & 7;
    const int b = bid >> 6;
    const int n = b * SEQ + qt * 64 + lane;

    float qv[32];
    {
        const ushort_t* qrow = qkvb + (size_t)n * 768 + hh * 32;
#pragma unroll
        for (int i = 0; i < 4; i++) {
            uint4 u = *(const uint4*)(qrow + i * 8);
            cvt8(u, &qv[i * 8]);
        }
    }
    float l = 0.f;
    float acc[32] = {};
    for (int t = 0; t < 4; t++) {
        __syncthreads();   // smem reuse barrier
        const int kbase = b * SEQ + t * 128;
        // stage: 1024 16B chunks (128 keys x 8: 4 K-chunks + 4 V-chunks)
#pragma unroll
        for (int c = tid; c < 1024; c += 256) {
            const int key = c >> 3;
            const int part = c & 7;
            const int qoff = (part & 4) ? 512 : 256;
            const ushort_t* src = qkvb + (size_t)(kbase + key) * 768 + qoff + hh * 32 + (part & 3) * 8;
            uint4 u = *(const uint4*)src;
            float f[8]; cvt8(u, f);
            float* dst = &smem[((part & 4) ? 4096 : 0) + key * 32 + (part & 3) * 8];
            *(float4*)dst       = make_float4(f[0], f[1], f[2], f[3]);
            *(float4*)(dst + 4) = make_float4(f[4], f[5], f[6], f[7]);
        }
        if (tid < 128) smem[8192 + tid] = (float)pad[kbase + tid];
        __syncthreads();
        const int k0 = wave * 32;
        for (int k = k0; k < k0 + 32; k++) {
            const float* kr = &smem[k * 32];
            float s0 = 0, s1 = 0, s2 = 0, s3 = 0;
#pragma unroll
            for (int i = 0; i < 8; i++) {
                float4 kvv = *(const float4*)(kr + i * 4);
                s0 += qv[i * 4 + 0] * kvv.x; s1 += qv[i * 4 + 1] * kvv.y;
                s2 += qv[i * 4 + 2] * kvv.z; s3 += qv[i * 4 + 3] * kvv.w;
            }
            float s = ((s0 + s1) + (s2 + s3)) * 0.17677669529663687f;
            if (smem[8192 + k] != 0.f) s = -1e9f;
            const float p = __expf(s);
            l += p;
            const float* vr = &smem[4096 + k * 32];
#pragma unroll
            for (int i = 0; i < 8; i++) {
                float4 vv = *(const float4*)(vr + i * 4);
                acc[i * 4 + 0] += p * vv.x; acc[i * 4 + 1] += p * vv.y;
                acc[i * 4 + 2] += p * vv.z; acc[i * 4 + 3] += p * vv.w;
            }
        }
    }
    __syncthreads();
    if (wave != 0) {
        float* dst = &smem[(wave - 1) * 2112 + lane * 33];
#pragma unroll
        for (int i = 0; i < 32; i++) dst[i] = acc[i];
        dst[32] = l;
    }
    __syncthreads();
    if (wave == 0) {
#pragma unroll
        for (int w = 0; w < 3; w++) {
            const float* srcp = &smem[w * 2112 + lane * 33];
#pragma unroll
            for (int i = 0; i < 32; i++) acc[i] += srcp[i];
            l += srcp[32];
        }
        const float inv = 1.f / l;
        ushort_t* outp = ctxb + (size_t)n * 256 + hh * 32;
        ushort_t t16[32];
#pragma unroll
        for (int i = 0; i < 32; i++) t16[i] = bf16r(acc[i] * inv);
#pragma unroll
        for (int i = 0; i < 4; i++) *(uint4*)(outp + i * 8) = *(uint4*)&t16[i * 8];
    }
}

// ---------------------------------------------------------------------------
// Residual add + LayerNorm (in place into h, plus bf16 copy hb).
// ---------------------------------------------------------------------------
__global__ __launch_bounds__(256) void add_ln(
    float* __restrict__ h, const float* __restrict__ add,
    const float* __restrict__ g, const float* __restrict__ b,
    ushort_t* __restrict__ hb)
{
    __shared__ float red[256];
    const int n = blockIdx.x;
    const int d = threadIdx.x;
    const float v = h[n * D_MODEL + d] + add[n * D_MODEL + d];
    red[d] = v;
    __syncthreads();
    for (int st = 128; st > 0; st >>= 1) {
        if (d < st) red[d] += red[d + st];
        __syncthreads();
    }
    const float mu = red[0] * (1.0f / 256.0f);
    __syncthreads();
    const float c = v - mu;
    red[d] = c * c;
    __syncthreads();
    for (int st = 128; st > 0; st >>= 1) {
        if (d < st) red[d] += red[d + st];
        __syncthreads();
    }
    const float var = red[0] * (1.0f / 256.0f);
    const float o = c * rsqrtf(var + 1e-5f) * g[d] + b[d];
    h[n * D_MODEL + d] = o;
    hb[n * D_MODEL + d] = bf16r(o);
}

// ---------------------------------------------------------------------------
// Gate (fp32 for routing stability): softmax top-1 + bucket position.
// ---------------------------------------------------------------------------
__global__ __launch_bounds__(64) void gate_kernel(
    const float* __restrict__ h, const float* __restrict__ gw,
    const float* __restrict__ gb, int* __restrict__ top_idx,
    float* __restrict__ top_w, int* __restrict__ pos, int* __restrict__ counts)
{
    const int n = blockIdx.x;
    const int lane = threadIdx.x;
    float part[NE] = {};
    for (int d = lane; d < D_MODEL; d += 64) {
        const float hv = h[n * D_MODEL + d];
#pragma unroll
        for (int e = 0; e < NE; e++) part[e] += hv * gw[e * D_MODEL + d];
    }
#pragma unroll
    for (int e = 0; e < NE; e++) {
        float v = part[e];
        for (int o = 32; o > 0; o >>= 1) v += __shfl_down(v, o, 64);
        part[e] = v;
    }
    if (lane == 0) {
        float lg[NE];
        float best = -1e30f; int bi = 0;
#pragma unroll
        for (int e = 0; e < NE; e++) {
            lg[e] = part[e] + gb[e];
            if (lg[e] > best) { best = lg[e]; bi = e; }
        }
        float ssum = 0.0f;
#pragma unroll
        for (int e = 0; e < NE; e++) ssum += __expf(lg[e] - best);
        top_idx[n] = bi;
        top_w[n] = 1.0f / ssum;
        pos[n] = atomicAdd(&counts[bi], 1);
    }
}

__global__ void offsets_kernel(const int* __restrict__ counts, int* __restrict__ offs)
{
    if (threadIdx.x == 0 && blockIdx.x == 0) {
        int a = 0;
        for (int e = 0; e < NE; e++) { offs[e] = a; a += counts[e]; }
    }
}

__global__ __launch_bounds__(256) void scatter_perm(
    const int* __restrict__ top_idx, const int* __restrict__ pos,
    const int* __restrict__ offs, int* __restrict__ perm)
{
    const int n = blockIdx.x * 256 + threadIdx.x;
    if (n < NTOK) perm[offs[top_idx[n]] + pos[n]] = n;
}

// ---------------------------------------------------------------------------
// Masked mean pool + classifier head (fp32).
// ---------------------------------------------------------------------------
__global__ __launch_bounds__(256) void pool_kernel(
    const float* __restrict__ h, const int* __restrict__ pad,
    float* __restrict__ pooled)
{
    const int b = blockIdx.x;
    const int d = threadIdx.x;
    float s = 0.0f, cnt = 0.0f;
    for (int i = 0; i < SEQ; i++) {
        if (!pad[b * SEQ + i]) {
            s += h[(size_t)(b * SEQ + i) * D_MODEL + d];
            cnt += 1.0f;
        }
    }
    pooled[b * D_MODEL + d] = s / fmaxf(cnt, 1.0f);
}

__global__ __launch_bounds__(128) void cls_kernel(
    const float* __restrict__ pooled, const float* __restrict__ fc1w,
    const float* __restrict__ fc1b, const float* __restrict__ fc2w,
    const float* __restrict__ fc2b, float* __restrict__ out)
{
    __shared__ float zs[128];
    const int b = blockIdx.x;
    const int j = threadIdx.x;
    float s = fc1b[j];
    for (int d = 0; d < D_MODEL; d++) s += pooled[b * D_MODEL + d] * fc1w[j * D_MODEL + d];
    zs[j] = fmaxf(s, 0.0f);
    __syncthreads();
    if (j < 2) {
        float o = fc2b[j];
        for (int i = 0; i < 128; i++) o += zs[i] * fc2w[j * 128 + i];
        out[b * 2 + j] = o;
    }
}

// ---------------------------------------------------------------------------
extern "C" void kernel_launch(void* const* d_in, const int* in_sizes, int n_in,
                              void* d_out, int out_size, void* d_ws, size_t ws_size,
                              hipStream_t stream)
{
    const int*   x          = (const int*)d_in[0];
    const float* emb        = (const float*)d_in[1];
    const float* in_proj_w  = (const float*)d_in[2];
    const float* in_proj_b  = (const float*)d_in[3];
    const float* out_proj_w = (const float*)d_in[4];
    const float* out_proj_b = (const float*)d_in[5];
    const float* ln1_g      = (const float*)d_in[6];
    const float* ln1_b      = (const float*)d_in[7];
    const float* ln2_g      = (const float*)d_in[8];
    const float* ln2_b      = (const float*)d_in[9];
    const float* gate_w     = (const float*)d_in[10];
    const float* gate_b     = (const float*)d_in[11];
    const float* w1         = (const float*)d_in[12];
    const float* b1         = (const float*)d_in[13];
    const float* w2         = (const float*)d_in[14];
    const float* b2         = (const float*)d_in[15];
    const float* fc1_w      = (const float*)d_in[16];
    const float* fc1_b      = (const float*)d_in[17];
    const float* fc2_w      = (const float*)d_in[18];
    const float* fc2_b      = (const float*)d_in[19];
    float* out = (float*)d_out;

    // workspace layout (float slots)
    float* ws = (float*)d_ws;
    float*    h      = ws;                          // 2,097,152 f (8MB)
    float*    tmp    = ws + 2097152;                // 2,097,152 f (8MB)
    ushort_t* qkvb   = (ushort_t*)(ws + 4194304);   // 8192*768 bf16 (12MB)
    ushort_t* ctxb   = (ushort_t*)(ws + 7340032);   // 8192*256 bf16 (4MB)
    ushort_t* ehb    = (ushort_t*)(ws + 4194304);   // 8192*1024 bf16 aliases qkvb+ctxb
    ushort_t* hb     = (ushort_t*)(ws + 8388608);   // 8192*256 bf16 (4MB)
    ushort_t* wb     = (ushort_t*)(ws + 9437184);   // up to 2,097,152 bf16 (4MB)
    float*    top_w  = ws + 10485760;               // 8192
    float*    pooled = ws + 10493952;               // 4096
    int* ipart   = (int*)(ws + 10498048);
    int* pad     = ipart;              // 8192
    int* top_idx = ipart + 8192;
    int* pos     = ipart + 16384;
    int* perm    = ipart + 24576;
    int* counts  = ipart + 32768;      // 8
    int* offs    = ipart + 32776;      // 8

    embed_kernel<<<NTOK, 256, 0, stream>>>(x, emb, h, hb, pad);

    for (int l = 0; l < 2; l++) {
        // --- qkv projection (bf16 MFMA): [8192,256] x [768,256]^T -> qkvb ---
        wconv<<<192, 256, 0, stream>>>(in_proj_w + (size_t)l * 196608, wb, 196608);
        mfma_gemm<<<dim3(768 / 64, NTOK / 64, 1), 256, 0, stream>>>(
            hb, wb, in_proj_b + l * 768, qkvb, NTOK, 768, 256,
            nullptr, nullptr, nullptr, nullptr, GF_OUTBF16);
        // --- attention -> ctxb (bf16) ---
        attn_kernel<<<NB * NH * (SEQ / 64), 256, 0, stream>>>(qkvb, pad, ctxb);
        // --- output projection -> tmp (fp32) ---
        wconv<<<64, 256, 0, stream>>>(out_proj_w + (size_t)l * 65536, wb, 65536);
        mfma_gemm<<<dim3(256 / 64, NTOK / 64, 1), 256, 0, stream>>>(
            ctxb, wb, out_proj_b + l * 256, tmp, NTOK, 256, 256,
            nullptr, nullptr, nullptr, nullptr, 0);
        add_ln<<<NTOK, 256, 0, stream>>>(h, tmp, ln1_g + l * 256, ln1_b + l * 256, hb);
        // --- MoE routing (fp32) ---
        hipMemsetAsync(counts, 0, NE * sizeof(int), stream);
        gate_kernel<<<NTOK, 64, 0, stream>>>(
            h, gate_w + l * NE * 256, gate_b + l * NE, top_idx, top_w, pos, counts);
        offsets_kernel<<<1, 1, 0, stream>>>(counts, offs);
        scatter_perm<<<NTOK / 256, 256, 0, stream>>>(top_idx, pos, offs, perm);
        // --- MoE expert GEMMs (routed expert only, bf16 MFMA) ---
        wconv<<<2048, 256, 0, stream>>>(w1 + (size_t)l * 2097152, wb, 2097152);
        mfma_gemm<<<dim3(EHID / 64, NTOK / 64, NE), 256, 0, stream>>>(
            hb, wb, b1 + l * NE * EHID, ehb, 0, EHID, 256,
            counts, offs, perm, nullptr, GF_GATHER | GF_RELU | GF_OUTBF16);
        wconv<<<2048, 256, 0, stream>>>(w2 + (size_t)l * 2097152, wb, 2097152);
        mfma_gemm<<<dim3(D_MODEL / 64, NTOK / 64, NE), 256, 0, stream>>>(
            ehb, wb, b2 + l * NE * 256, tmp, 0, D_MODEL, 1024,
            counts, offs, perm, top_w, GF_SCATTER);
        add_ln<<<NTOK, 256, 0, stream>>>(h, tmp, ln2_g + l * 256, ln2_b + l * 256, hb);
    }

    pool_kernel<<<NB, 256, 0, stream>>>(h, pad, pooled);
    cls_kernel<<<NB, 128, 0, stream>>>(pooled, fc1_w, fc1_b, fc2_w, fc2_b, out);
}

// Round 3
// 596.350 us; speedup vs baseline: 3.5142x; 1.4770x over previous
//
#include <hip/hip_runtime.h>
#include <math.h>

// Model dims
#define D_MODEL 256
#define NTOK    8192      // B*S
#define SEQ     512
#define NB      16
#define NH      8
#define DHEAD   32
#define NE      8
#define EHID    1024

typedef __attribute__((ext_vector_type(8))) short short8;
typedef __attribute__((ext_vector_type(4))) float floatx4;
typedef unsigned short ushort_t;

__device__ __forceinline__ ushort_t bf16r(float f) {
    unsigned int u = __float_as_uint(f);
    u += 0x7fffu + ((u >> 16) & 1u);     // round-to-nearest-even
    return (ushort_t)(u >> 16);
}
__device__ __forceinline__ float bf2f(ushort_t b) {
    return __uint_as_float(((unsigned)b) << 16);
}

// ---------------------------------------------------------------------------
// fp32 -> bf16 conversion (weights)
// ---------------------------------------------------------------------------
__global__ __launch_bounds__(256) void wconv(
    const float* __restrict__ src, ushort_t* __restrict__ dst, int n)
{
    const int i = (blockIdx.x * 256 + threadIdx.x) * 4;
    if (i < n) {
        float4 v = *(const float4*)(src + i);
        ushort_t o[4] = { bf16r(v.x), bf16r(v.y), bf16r(v.z), bf16r(v.w) };
        *(uint2*)(dst + i) = *(uint2*)o;
    }
}

// ---------------------------------------------------------------------------
// Embedding + positional encoding + pad mask. Writes h (fp32) and hb (bf16).
// ---------------------------------------------------------------------------
__global__ __launch_bounds__(256) void embed_kernel(
    const int* __restrict__ x, const float* __restrict__ emb,
    float* __restrict__ h, ushort_t* __restrict__ hb, int* __restrict__ pad)
{
    __shared__ float wred[4];
    const int n = blockIdx.x;
    const int d = threadIdx.x;
    const int wave = d >> 6;
    const int s = n & (SEQ - 1);
    const int tok = x[n];
    float v = emb[tok * D_MODEL + d] * 16.0f;   // sqrt(256)
    const int j = d >> 1;
    const float c = -9.210340371976184f / 256.0f;    // -ln(10000)/256
    const float div = expf((float)(2 * j) * c);
    const float ang = (float)s * div;
    v += (d & 1) ? cosf(ang) : sinf(ang);
    h[n * D_MODEL + d] = v;
    hb[n * D_MODEL + d] = bf16r(v);
    float sm = v;
    for (int o = 1; o < 64; o <<= 1) sm += __shfl_xor(sm, o);
    if ((d & 63) == 0) wred[wave] = sm;
    __syncthreads();
    if (d == 0) pad[n] = ((wred[0] + wred[1] + wred[2] + wred[3]) == 0.0f) ? 1 : 0;
}

// ---------------------------------------------------------------------------
// Generic bf16 MFMA GEMM: C[M,N] = A[M,K] @ B[N,K]^T + bias[N]
// 64x64 tile, BK=64, 256 threads (4 waves, 2x2), mfma_f32_16x16x32_bf16.
// Segmented (MoE) mode when counts != nullptr: blockIdx.z = expert, segment
// offset computed by an inline 8-wide prefix over counts.
// ---------------------------------------------------------------------------
#define GF_RELU    1
#define GF_OUTBF16 2
#define GF_GATHER  4
#define GF_SCATTER 8

__global__ __launch_bounds__(256) void mfma_gemm(
    const ushort_t* __restrict__ A, const ushort_t* __restrict__ Bw,
    const float* __restrict__ bias, void* __restrict__ Cout,
    int M, int N, int K,
    const int* __restrict__ counts,
    const int* __restrict__ perm, const float* __restrict__ topw,
    int flags)
{
    __shared__ ushort_t As[64][72];   // 64 rows x (64 + 8 pad) bf16
    __shared__ ushort_t Bs[64][72];
    const int e = blockIdx.z;
    int cnt, off = 0;
    if (counts) {
        cnt = counts[e];
        if ((int)blockIdx.y * 64 >= cnt) return;
        for (int i = 0; i < e; i++) off += counts[i];
    } else { cnt = M; }
    const ushort_t* Bp = Bw + (size_t)e * N * K;
    const float* bp = bias + (size_t)e * N;
    const int m0 = blockIdx.y * 64, n0 = blockIdx.x * 64;
    const int tid = threadIdx.x;
    const int sr0 = tid >> 3;          // 0..31
    const int kc0 = (tid & 7) * 8;     // 0..56
    const int r0 = m0 + sr0, r1 = r0 + 32;
    const bool v0 = r0 < cnt, v1 = r1 < cnt;
    size_t a0, a1;
    if (flags & GF_GATHER) {
        a0 = (size_t)perm[off + (v0 ? r0 : 0)];
        a1 = (size_t)perm[off + (v1 ? r1 : 0)];
    } else {
        a0 = (size_t)(off + (v0 ? r0 : 0));
        a1 = (size_t)(off + (v1 ? r1 : 0));
    }
    const ushort_t* Ap0 = A + a0 * K + kc0;
    const ushort_t* Ap1 = A + a1 * K + kc0;
    const ushort_t* Bp0 = Bp + (size_t)(n0 + sr0) * K + kc0;
    const ushort_t* Bp1 = Bp + (size_t)(n0 + sr0 + 32) * K + kc0;
    const int lane = tid & 63, wave = tid >> 6;
    const int wm = (wave & 1) * 32, wn = (wave >> 1) * 32;
    const int fr = lane & 15, fk = (lane >> 4) * 8;
    floatx4 acc[2][2];
#pragma unroll
    for (int i = 0; i < 2; i++)
#pragma unroll
        for (int jj = 0; jj < 2; jj++) acc[i][jj] = (floatx4){0.f, 0.f, 0.f, 0.f};

    for (int k0 = 0; k0 < K; k0 += 64) {
        uint4 av0 = *(const uint4*)(Ap0 + k0);
        uint4 av1 = *(const uint4*)(Ap1 + k0);
        uint4 bv0 = *(const uint4*)(Bp0 + k0);
        uint4 bv1 = *(const uint4*)(Bp1 + k0);
        __syncthreads();
        *(uint4*)&As[sr0][kc0]      = av0;
        *(uint4*)&As[sr0 + 32][kc0] = av1;
        *(uint4*)&Bs[sr0][kc0]      = bv0;
        *(uint4*)&Bs[sr0 + 32][kc0] = bv1;
        __syncthreads();
#pragma unroll
        for (int ks = 0; ks < 2; ks++) {
            const int ko = ks * 32 + fk;
            short8 fa0 = *(const short8*)&As[wm + fr][ko];
            short8 fa1 = *(const short8*)&As[wm + 16 + fr][ko];
            short8 fb0 = *(const short8*)&Bs[wn + fr][ko];
            short8 fb1 = *(const short8*)&Bs[wn + 16 + fr][ko];
            acc[0][0] = __builtin_amdgcn_mfma_f32_16x16x32_bf16(fa0, fb0, acc[0][0], 0, 0, 0);
            acc[0][1] = __builtin_amdgcn_mfma_f32_16x16x32_bf16(fa0, fb1, acc[0][1], 0, 0, 0);
            acc[1][0] = __builtin_amdgcn_mfma_f32_16x16x32_bf16(fa1, fb0, acc[1][0], 0, 0, 0);
            acc[1][1] = __builtin_amdgcn_mfma_f32_16x16x32_bf16(fa1, fb1, acc[1][1], 0, 0, 0);
        }
    }
    const int crow0 = (lane >> 4) * 4;
    const int ccol = lane & 15;
#pragma unroll
    for (int fm = 0; fm < 2; fm++) {
#pragma unroll
        for (int fn = 0; fn < 2; fn++) {
            const int gcol = n0 + wn + fn * 16 + ccol;
            const float bsv = bp[gcol];
#pragma unroll
            for (int r = 0; r < 4; r++) {
                const int grow = m0 + wm + fm * 16 + crow0 + r;
                if (grow >= cnt) continue;
                float v = acc[fm][fn][r] + bsv;
                if (flags & GF_RELU) v = fmaxf(v, 0.f);
                if (flags & GF_SCATTER) {
                    const int tok = perm[off + grow];
                    ((float*)Cout)[(size_t)tok * N + gcol] = v * topw[tok];
                } else if (flags & GF_OUTBF16) {
                    ((ushort_t*)Cout)[(size_t)(off + grow) * N + gcol] = bf16r(v);
                } else {
                    ((float*)Cout)[(size_t)(off + grow) * N + gcol] = v;
                }
            }
        }
    }
}

// ---------------------------------------------------------------------------
// MFMA flash-style attention. Block = one (b, h, 64-query tile); 4 waves of
// 16 queries each. Per 64-key tile: S = Q K^T via mfma_16x16x32 (K=32=DH),
// no-max-sub softmax in C-layout, P (bf16) -> LDS (per-wave-private rows),
// PV via mfma with V^T staged (swizzled) in LDS. grid = 1024 x 256.
// ---------------------------------------------------------------------------
__global__ __launch_bounds__(256) void attn_kernel(
    const ushort_t* __restrict__ qkvb, const int* __restrict__ pad,
    ushort_t* __restrict__ ctxb)
{
    __shared__ ushort_t Kt[64 * 40];     // [key][40] rows (80 B, 16B-aligned)
    __shared__ ushort_t Vt[32 * 72];     // [d][72], key index swizzled
    __shared__ ushort_t Ps[64 * 72];     // [q][72]
    __shared__ float padf[512];
    const int tid = threadIdx.x;
    const int lane = tid & 63;
    const int wave = tid >> 6;
    const int quad = lane >> 4;
    const int l16  = lane & 15;
    const int bid = blockIdx.x;
    const int qt = bid & 7;
    const int hh = (bid >> 3) & 7;
    const int b = bid >> 6;
    const int q0 = wave * 16;

    padf[tid]       = (float)pad[b * SEQ + tid];
    padf[tid + 256] = (float)pad[b * SEQ + 256 + tid];

    // Q fragment (A-layout): row = l16 -> query q0+l16, k = quad*8.. -> d
    short8 qfrag = *(const short8*)(qkvb +
        (size_t)(b * SEQ + qt * 64 + q0 + l16) * 768 + hh * 32 + quad * 8);

    const int skey = tid >> 2;          // 0..63
    const int schunk = (tid & 3) * 8;   // 0,8,16,24

    floatx4 o0 = {0.f,0.f,0.f,0.f}, o1 = {0.f,0.f,0.f,0.f};
    float lsum[4] = {0.f, 0.f, 0.f, 0.f};
    const float scale = 0.17677669529663687f;   // 1/sqrt(32)

    for (int t = 0; t < 8; t++) {
        const int kbase = b * SEQ + t * 64;
        __syncthreads();
        // K tile: straight copy [key][d]
        uint4 kv = *(const uint4*)(qkvb + (size_t)(kbase + skey) * 768 + 256 + hh * 32 + schunk);
        *(uint4*)&Kt[skey * 40 + schunk] = kv;
        // V tile: transpose into Vt[d][key] with 8-block swizzle
        uint4 vv = *(const uint4*)(qkvb + (size_t)(kbase + skey) * 768 + 512 + hh * 32 + schunk);
        ushort_t vs[8]; *(uint4*)vs = vv;
#pragma unroll
        for (int j = 0; j < 8; j++) {
            const int d = schunk + j;
            Vt[d * 72 + (skey ^ ((d >> 3) << 3))] = vs[j];
        }
        __syncthreads();
        // scores: 4 B-frags of 16 keys each
        floatx4 sfr[4];
#pragma unroll
        for (int fn = 0; fn < 4; fn++) {
            short8 kf = *(const short8*)&Kt[(fn * 16 + l16) * 40 + quad * 8];
            sfr[fn] = __builtin_amdgcn_mfma_f32_16x16x32_bf16(
                qfrag, kf, (floatx4){0.f,0.f,0.f,0.f}, 0, 0, 0);
        }
        // softmax (no max-sub) + write P (bf16) into this wave's Ps rows
#pragma unroll
        for (int fn = 0; fn < 4; fn++) {
            const int keyl = fn * 16 + l16;
            const float pv = padf[t * 64 + keyl];
#pragma unroll
            for (int r = 0; r < 4; r++) {
                float p = (pv != 0.f) ? 0.f : __expf(sfr[fn][r] * scale);
                ushort_t pb = bf16r(p);
                lsum[r] += bf2f(pb);   // rounded value: consistent num/denom
                Ps[(q0 + quad * 4 + r) * 72 + keyl] = pb;
            }
        }
        // PV: A from own Ps rows (same-wave write->read, no barrier needed)
#pragma unroll
        for (int kc = 0; kc < 2; kc++) {
            short8 pf = *(const short8*)&Ps[(q0 + l16) * 72 + kc * 32 + quad * 8];
            {
                const int d = l16;
                short8 vf = *(const short8*)&Vt[d * 72 + ((kc * 32 + quad * 8) ^ ((d >> 3) << 3))];
                o0 = __builtin_amdgcn_mfma_f32_16x16x32_bf16(pf, vf, o0, 0, 0, 0);
            }
            {
                const int d = 16 + l16;
                short8 vf = *(const short8*)&Vt[d * 72 + ((kc * 32 + quad * 8) ^ ((d >> 3) << 3))];
                o1 = __builtin_amdgcn_mfma_f32_16x16x32_bf16(pf, vf, o1, 0, 0, 0);
            }
        }
    }
    // reduce l across the 16 lanes of each quad (rows live in quad groups)
#pragma unroll
    for (int r = 0; r < 4; r++) {
        float v = lsum[r];
        v += __shfl_xor(v, 1); v += __shfl_xor(v, 2);
        v += __shfl_xor(v, 4); v += __shfl_xor(v, 8);
        lsum[r] = 1.f / v;
    }
    const int nq = b * SEQ + qt * 64 + q0 + quad * 4;
#pragma unroll
    for (int r = 0; r < 4; r++) {
        ushort_t* outp = ctxb + (size_t)(nq + r) * 256 + hh * 32;
        outp[l16]      = bf16r(o0[r] * lsum[r]);
        outp[16 + l16] = bf16r(o1[r] * lsum[r]);
    }
}

// ---------------------------------------------------------------------------
// Residual add + LayerNorm (in place into h, plus bf16 copy hb).
// ---------------------------------------------------------------------------
__global__ __launch_bounds__(256) void add_ln(
    float* __restrict__ h, const float* __restrict__ add,
    const float* __restrict__ g, const float* __restrict__ b,
    ushort_t* __restrict__ hb)
{
    __shared__ float wred[8];
    const int n = blockIdx.x;
    const int d = threadIdx.x;
    const int wave = d >> 6;
    const float v = h[n * D_MODEL + d] + add[n * D_MODEL + d];
    float s = v;
    for (int o = 1; o < 64; o <<= 1) s += __shfl_xor(s, o);
    if ((d & 63) == 0) wred[wave] = s;
    __syncthreads();
    const float mu = (wred[0] + wred[1] + wred[2] + wred[3]) * (1.0f / 256.0f);
    const float c = v - mu;
    float cs = c * c;
    for (int o = 1; o < 64; o <<= 1) cs += __shfl_xor(cs, o);
    if ((d & 63) == 0) wred[4 + wave] = cs;
    __syncthreads();
    const float var = (wred[4] + wred[5] + wred[6] + wred[7]) * (1.0f / 256.0f);
    const float o = c * rsqrtf(var + 1e-5f) * g[d] + b[d];
    h[n * D_MODEL + d] = o;
    hb[n * D_MODEL + d] = bf16r(o);
}

// ---------------------------------------------------------------------------
// Gate (fp32 for routing stability): 4 tokens per block, one wave each.
// ---------------------------------------------------------------------------
__global__ __launch_bounds__(256) void gate_kernel(
    const float* __restrict__ h, const float* __restrict__ gw,
    const float* __restrict__ gb, int* __restrict__ top_idx,
    float* __restrict__ top_w, int* __restrict__ pos, int* __restrict__ counts)
{
    const int wave = threadIdx.x >> 6;
    const int lane = threadIdx.x & 63;
    const int n = blockIdx.x * 4 + wave;
    float part[NE] = {};
#pragma unroll
    for (int i = 0; i < 4; i++) {
        const int d = lane + i * 64;
        const float hv = h[n * D_MODEL + d];
#pragma unroll
        for (int e = 0; e < NE; e++) part[e] += hv * gw[e * D_MODEL + d];
    }
#pragma unroll
    for (int e = 0; e < NE; e++) {
        float v = part[e];
        for (int o = 1; o < 64; o <<= 1) v += __shfl_xor(v, o);
        part[e] = v;
    }
    if (lane == 0) {
        float lg[NE];
        float best = -1e30f; int bi = 0;
#pragma unroll
        for (int e = 0; e < NE; e++) {
            lg[e] = part[e] + gb[e];
            if (lg[e] > best) { best = lg[e]; bi = e; }
        }
        float ssum = 0.0f;
#pragma unroll
        for (int e = 0; e < NE; e++) ssum += __expf(lg[e] - best);
        top_idx[n] = bi;
        top_w[n] = 1.0f / ssum;
        pos[n] = atomicAdd(&counts[bi], 1);
    }
}

__global__ __launch_bounds__(256) void scatter_perm(
    const int* __restrict__ top_idx, const int* __restrict__ pos,
    const int* __restrict__ counts, int* __restrict__ perm)
{
    __shared__ int offs_s[NE];
    if (threadIdx.x < NE) {
        int a = 0;
        for (int i = 0; i < (int)threadIdx.x; i++) a += counts[i];
        offs_s[threadIdx.x] = a;
    }
    __syncthreads();
    const int n = blockIdx.x * 256 + threadIdx.x;
    if (n < NTOK) perm[offs_s[top_idx[n]] + pos[n]] = n;
}

// ---------------------------------------------------------------------------
// Masked mean pool, stage 1: 16x16 blocks, partial sums via atomics.
// ---------------------------------------------------------------------------
__global__ __launch_bounds__(256) void pool1(
    const float* __restrict__ h, const int* __restrict__ pad,
    float* __restrict__ pooled, float* __restrict__ cntb)
{
    const int b = blockIdx.x, c = blockIdx.y, d = threadIdx.x;
    float s = 0.0f; int cnt = 0;
    for (int i = 0; i < 32; i++) {
        const int idx = b * SEQ + c * 32 + i;
        if (!pad[idx]) { s += h[(size_t)idx * D_MODEL + d]; cnt++; }
    }
    atomicAdd(&pooled[b * D_MODEL + d], s);
    if (d == 0) atomicAdd(&cntb[b], (float)cnt);
}

__global__ __launch_bounds__(128) void cls_kernel(
    const float* __restrict__ pooled, const float* __restrict__ cntb,
    const float* __restrict__ fc1w, const float* __restrict__ fc1b,
    const float* __restrict__ fc2w, const float* __restrict__ fc2b,
    float* __restrict__ out)
{
    __shared__ float zs[128];
    const int b = blockIdx.x;
    const int j = threadIdx.x;
    const float invc = 1.0f / fmaxf(cntb[b], 1.0f);
    float s = 0.0f;
    for (int d = 0; d < D_MODEL; d++) s += pooled[b * D_MODEL + d] * fc1w[j * D_MODEL + d];
    zs[j] = fmaxf(s * invc + fc1b[j], 0.0f);
    __syncthreads();
    if (j < 2) {
        float o = fc2b[j];
        for (int i = 0; i < 128; i++) o += zs[i] * fc2w[j * 128 + i];
        out[b * 2 + j] = o;
    }
}

// ---------------------------------------------------------------------------
extern "C" void kernel_launch(void* const* d_in, const int* in_sizes, int n_in,
                              void* d_out, int out_size, void* d_ws, size_t ws_size,
                              hipStream_t stream)
{
    const int*   x          = (const int*)d_in[0];
    const float* emb        = (const float*)d_in[1];
    const float* in_proj_w  = (const float*)d_in[2];
    const float* in_proj_b  = (const float*)d_in[3];
    const float* out_proj_w = (const float*)d_in[4];
    const float* out_proj_b = (const float*)d_in[5];
    const float* ln1_g      = (const float*)d_in[6];
    const float* ln1_b      = (const float*)d_in[7];
    const float* ln2_g      = (const float*)d_in[8];
    const float* ln2_b      = (const float*)d_in[9];
    const float* gate_w     = (const float*)d_in[10];
    const float* gate_b     = (const float*)d_in[11];
    const float* w1         = (const float*)d_in[12];
    const float* b1         = (const float*)d_in[13];
    const float* w2         = (const float*)d_in[14];
    const float* b2         = (const float*)d_in[15];
    const float* fc1_w      = (const float*)d_in[16];
    const float* fc1_b      = (const float*)d_in[17];
    const float* fc2_w      = (const float*)d_in[18];
    const float* fc2_b      = (const float*)d_in[19];
    float* out = (float*)d_out;

    // workspace layout (float slots)
    float* ws = (float*)d_ws;
    float*    h      = ws;                          // 2,097,152 f
    float*    tmp    = ws + 2097152;                // 2,097,152 f
    ushort_t* qkvb   = (ushort_t*)(ws + 4194304);   // 8192*768 bf16
    ushort_t* ctxb   = (ushort_t*)(ws + 7340032);   // 8192*256 bf16
    ushort_t* ehb    = (ushort_t*)(ws + 4194304);   // 8192*1024 bf16 aliases qkvb+ctxb
    ushort_t* hb     = (ushort_t*)(ws + 8388608);   // 8192*256 bf16
    ushort_t* wb     = (ushort_t*)(ws + 9437184);   // up to 2,097,152 bf16
    float*    top_w  = ws + 10485760;               // 8192
    float*    pooled = ws + 10493952;               // 4096
    float*    cntb   = ws + 10498048;               // 16
    int* ipart   = (int*)(ws + 10498064);
    int* pad     = ipart;              // 8192
    int* top_idx = ipart + 8192;
    int* pos     = ipart + 16384;
    int* perm    = ipart + 24576;
    int* counts  = ipart + 32768;      // 8

    embed_kernel<<<NTOK, 256, 0, stream>>>(x, emb, h, hb, pad);
    hipMemsetAsync(pooled, 0, (NB * D_MODEL + NB) * sizeof(float), stream);

    for (int l = 0; l < 2; l++) {
        // --- qkv projection (bf16 MFMA) ---
        wconv<<<192, 256, 0, stream>>>(in_proj_w + (size_t)l * 196608, wb, 196608);
        mfma_gemm<<<dim3(768 / 64, NTOK / 64, 1), 256, 0, stream>>>(
            hb, wb, in_proj_b + l * 768, qkvb, NTOK, 768, 256,
            nullptr, nullptr, nullptr, GF_OUTBF16);
        // --- attention (MFMA flash) -> ctxb ---
        attn_kernel<<<NB * NH * (SEQ / 64), 256, 0, stream>>>(qkvb, pad, ctxb);
        // --- output projection -> tmp (fp32) ---
        wconv<<<64, 256, 0, stream>>>(out_proj_w + (size_t)l * 65536, wb, 65536);
        mfma_gemm<<<dim3(256 / 64, NTOK / 64, 1), 256, 0, stream>>>(
            ctxb, wb, out_proj_b + l * 256, tmp, NTOK, 256, 256,
            nullptr, nullptr, nullptr, 0);
        add_ln<<<NTOK, 256, 0, stream>>>(h, tmp, ln1_g + l * 256, ln1_b + l * 256, hb);
        // --- MoE routing (fp32) ---
        hipMemsetAsync(counts, 0, NE * sizeof(int), stream);
        gate_kernel<<<NTOK / 4, 256, 0, stream>>>(
            h, gate_w + l * NE * 256, gate_b + l * NE, top_idx, top_w, pos, counts);
        scatter_perm<<<NTOK / 256, 256, 0, stream>>>(top_idx, pos, counts, perm);
        // --- MoE expert GEMMs (routed expert only, bf16 MFMA) ---
        wconv<<<2048, 256, 0, stream>>>(w1 + (size_t)l * 2097152, wb, 2097152);
        mfma_gemm<<<dim3(EHID / 64, NTOK / 64, NE), 256, 0, stream>>>(
            hb, wb, b1 + l * NE * EHID, ehb, 0, EHID, 256,
            counts, perm, nullptr, GF_GATHER | GF_RELU | GF_OUTBF16);
        wconv<<<2048, 256, 0, stream>>>(w2 + (size_t)l * 2097152, wb, 2097152);
        mfma_gemm<<<dim3(D_MODEL / 64, NTOK / 64, NE), 256, 0, stream>>>(
            ehb, wb, b2 + l * NE * 256, tmp, 0, D_MODEL, 1024,
            counts, perm, top_w, GF_SCATTER);
        add_ln<<<NTOK, 256, 0, stream>>>(h, tmp, ln2_g + l * 256, ln2_b + l * 256, hb);
    }

    pool1<<<dim3(NB, 16), 256, 0, stream>>>(h, pad, pooled, cntb);
    cls_kernel<<<NB, 128, 0, stream>>>(pooled, cntb, fc1_w, fc1_b, fc2_w, fc2_b, out);
}

// Round 4
// 466.859 us; speedup vs baseline: 4.4889x; 1.2774x over previous
//
#include <hip/hip_runtime.h>
#include <math.h>

// Model dims
#define D_MODEL 256
#define NTOK    8192      // B*S
#define SEQ     512
#define NB      16
#define NH      8
#define DHEAD   32
#define NE      8
#define EHID    1024
#define CSTRIDE 32        // counts[] cacheline stride (ints) to kill same-line atomic serialization

typedef __attribute__((ext_vector_type(8))) short short8;
typedef __attribute__((ext_vector_type(4))) float floatx4;
typedef unsigned short ushort_t;

__device__ __forceinline__ ushort_t bf16r(float f) {
    unsigned int u = __float_as_uint(f);
    u += 0x7fffu + ((u >> 16) & 1u);     // round-to-nearest-even
    return (ushort_t)(u >> 16);
}
__device__ __forceinline__ float bf2f(ushort_t b) {
    return __uint_as_float(((unsigned)b) << 16);
}

// ---------------------------------------------------------------------------
// fp32 -> bf16 conversion (weights)
// ---------------------------------------------------------------------------
__global__ __launch_bounds__(256) void wconv(
    const float* __restrict__ src, ushort_t* __restrict__ dst, int n)
{
    const int i = (blockIdx.x * 256 + threadIdx.x) * 4;
    if (i < n) {
        float4 v = *(const float4*)(src + i);
        ushort_t o[4] = { bf16r(v.x), bf16r(v.y), bf16r(v.z), bf16r(v.w) };
        *(uint2*)(dst + i) = *(uint2*)o;
    }
}

// ---------------------------------------------------------------------------
// Embedding + positional encoding + pad mask. Writes h (fp32) and hb (bf16).
// ---------------------------------------------------------------------------
__global__ __launch_bounds__(256) void embed_kernel(
    const int* __restrict__ x, const float* __restrict__ emb,
    float* __restrict__ h, ushort_t* __restrict__ hb, int* __restrict__ pad)
{
    __shared__ float wred[4];
    const int n = blockIdx.x;
    const int d = threadIdx.x;
    const int wave = d >> 6;
    const int s = n & (SEQ - 1);
    const int tok = x[n];
    float v = emb[tok * D_MODEL + d] * 16.0f;   // sqrt(256)
    const int j = d >> 1;
    const float c = -9.210340371976184f / 256.0f;    // -ln(10000)/256
    const float div = expf((float)(2 * j) * c);
    const float ang = (float)s * div;
    v += (d & 1) ? cosf(ang) : sinf(ang);
    h[n * D_MODEL + d] = v;
    hb[n * D_MODEL + d] = bf16r(v);
    float sm = v;
    for (int o = 1; o < 64; o <<= 1) sm += __shfl_xor(sm, o);
    if ((d & 63) == 0) wred[wave] = sm;
    __syncthreads();
    if (d == 0) pad[n] = ((wred[0] + wred[1] + wred[2] + wred[3]) == 0.0f) ? 1 : 0;
}

// ---------------------------------------------------------------------------
// Generic bf16 MFMA GEMM: C[M,N] = A[M,K] @ B[N,K]^T + bias[N]
// 64x64 tile, BK=64, 256 threads (4 waves, 2x2), mfma_f32_16x16x32_bf16.
// Segmented (MoE) mode when counts != nullptr (padded stride CSTRIDE).
// ---------------------------------------------------------------------------
#define GF_RELU    1
#define GF_OUTBF16 2
#define GF_GATHER  4
#define GF_SCATTER 8

__global__ __launch_bounds__(256) void mfma_gemm(
    const ushort_t* __restrict__ A, const ushort_t* __restrict__ Bw,
    const float* __restrict__ bias, void* __restrict__ Cout,
    int M, int N, int K,
    const int* __restrict__ counts,
    const int* __restrict__ perm, const float* __restrict__ topw,
    int flags)
{
    __shared__ ushort_t As[64][72];   // 64 rows x (64 + 8 pad) bf16
    __shared__ ushort_t Bs[64][72];
    const int e = blockIdx.z;
    int cnt, off = 0;
    if (counts) {
        cnt = counts[e * CSTRIDE];
        if ((int)blockIdx.y * 64 >= cnt) return;
        for (int i = 0; i < e; i++) off += counts[i * CSTRIDE];
    } else { cnt = M; }
    const ushort_t* Bp = Bw + (size_t)e * N * K;
    const float* bp = bias + (size_t)e * N;
    const int m0 = blockIdx.y * 64, n0 = blockIdx.x * 64;
    const int tid = threadIdx.x;
    const int sr0 = tid >> 3;          // 0..31
    const int kc0 = (tid & 7) * 8;     // 0..56
    const int r0 = m0 + sr0, r1 = r0 + 32;
    const bool v0 = r0 < cnt, v1 = r1 < cnt;
    size_t a0, a1;
    if (flags & GF_GATHER) {
        a0 = (size_t)perm[off + (v0 ? r0 : 0)];
        a1 = (size_t)perm[off + (v1 ? r1 : 0)];
    } else {
        a0 = (size_t)(off + (v0 ? r0 : 0));
        a1 = (size_t)(off + (v1 ? r1 : 0));
    }
    const ushort_t* Ap0 = A + a0 * K + kc0;
    const ushort_t* Ap1 = A + a1 * K + kc0;
    const ushort_t* Bp0 = Bp + (size_t)(n0 + sr0) * K + kc0;
    const ushort_t* Bp1 = Bp + (size_t)(n0 + sr0 + 32) * K + kc0;
    const int lane = tid & 63, wave = tid >> 6;
    const int wm = (wave & 1) * 32, wn = (wave >> 1) * 32;
    const int fr = lane & 15, fk = (lane >> 4) * 8;
    floatx4 acc[2][2];
#pragma unroll
    for (int i = 0; i < 2; i++)
#pragma unroll
        for (int jj = 0; jj < 2; jj++) acc[i][jj] = (floatx4){0.f, 0.f, 0.f, 0.f};

    for (int k0 = 0; k0 < K; k0 += 64) {
        uint4 av0 = *(const uint4*)(Ap0 + k0);
        uint4 av1 = *(const uint4*)(Ap1 + k0);
        uint4 bv0 = *(const uint4*)(Bp0 + k0);
        uint4 bv1 = *(const uint4*)(Bp1 + k0);
        __syncthreads();
        *(uint4*)&As[sr0][kc0]      = av0;
        *(uint4*)&As[sr0 + 32][kc0] = av1;
        *(uint4*)&Bs[sr0][kc0]      = bv0;
        *(uint4*)&Bs[sr0 + 32][kc0] = bv1;
        __syncthreads();
#pragma unroll
        for (int ks = 0; ks < 2; ks++) {
            const int ko = ks * 32 + fk;
            short8 fa0 = *(const short8*)&As[wm + fr][ko];
            short8 fa1 = *(const short8*)&As[wm + 16 + fr][ko];
            short8 fb0 = *(const short8*)&Bs[wn + fr][ko];
            short8 fb1 = *(const short8*)&Bs[wn + 16 + fr][ko];
            acc[0][0] = __builtin_amdgcn_mfma_f32_16x16x32_bf16(fa0, fb0, acc[0][0], 0, 0, 0);
            acc[0][1] = __builtin_amdgcn_mfma_f32_16x16x32_bf16(fa0, fb1, acc[0][1], 0, 0, 0);
            acc[1][0] = __builtin_amdgcn_mfma_f32_16x16x32_bf16(fa1, fb0, acc[1][0], 0, 0, 0);
            acc[1][1] = __builtin_amdgcn_mfma_f32_16x16x32_bf16(fa1, fb1, acc[1][1], 0, 0, 0);
        }
    }
    const int crow0 = (lane >> 4) * 4;
    const int ccol = lane & 15;
#pragma unroll
    for (int fm = 0; fm < 2; fm++) {
#pragma unroll
        for (int fn = 0; fn < 2; fn++) {
            const int gcol = n0 + wn + fn * 16 + ccol;
            const float bsv = bp[gcol];
#pragma unroll
            for (int r = 0; r < 4; r++) {
                const int grow = m0 + wm + fm * 16 + crow0 + r;
                if (grow >= cnt) continue;
                float v = acc[fm][fn][r] + bsv;
                if (flags & GF_RELU) v = fmaxf(v, 0.f);
                if (flags & GF_SCATTER) {
                    const int tok = perm[off + grow];
                    ((float*)Cout)[(size_t)tok * N + gcol] = v * topw[tok];
                } else if (flags & GF_OUTBF16) {
                    ((ushort_t*)Cout)[(size_t)(off + grow) * N + gcol] = bf16r(v);
                } else {
                    ((float*)Cout)[(size_t)(off + grow) * N + gcol] = v;
                }
            }
        }
    }
}

// ---------------------------------------------------------------------------
// MFMA flash-style attention (as round 3, verified).
// ---------------------------------------------------------------------------
__global__ __launch_bounds__(256) void attn_kernel(
    const ushort_t* __restrict__ qkvb, const int* __restrict__ pad,
    ushort_t* __restrict__ ctxb)
{
    __shared__ ushort_t Kt[64 * 40];
    __shared__ ushort_t Vt[32 * 72];
    __shared__ ushort_t Ps[64 * 72];
    __shared__ float padf[512];
    const int tid = threadIdx.x;
    const int lane = tid & 63;
    const int wave = tid >> 6;
    const int quad = lane >> 4;
    const int l16  = lane & 15;
    const int bid = blockIdx.x;
    const int qt = bid & 7;
    const int hh = (bid >> 3) & 7;
    const int b = bid >> 6;
    const int q0 = wave * 16;

    padf[tid]       = (float)pad[b * SEQ + tid];
    padf[tid + 256] = (float)pad[b * SEQ + 256 + tid];

    short8 qfrag = *(const short8*)(qkvb +
        (size_t)(b * SEQ + qt * 64 + q0 + l16) * 768 + hh * 32 + quad * 8);

    const int skey = tid >> 2;
    const int schunk = (tid & 3) * 8;

    floatx4 o0 = {0.f,0.f,0.f,0.f}, o1 = {0.f,0.f,0.f,0.f};
    float lsum[4] = {0.f, 0.f, 0.f, 0.f};
    const float scale = 0.17677669529663687f;

    for (int t = 0; t < 8; t++) {
        const int kbase = b * SEQ + t * 64;
        __syncthreads();
        uint4 kv = *(const uint4*)(qkvb + (size_t)(kbase + skey) * 768 + 256 + hh * 32 + schunk);
        *(uint4*)&Kt[skey * 40 + schunk] = kv;
        uint4 vv = *(const uint4*)(qkvb + (size_t)(kbase + skey) * 768 + 512 + hh * 32 + schunk);
        ushort_t vs[8]; *(uint4*)vs = vv;
#pragma unroll
        for (int j = 0; j < 8; j++) {
            const int d = schunk + j;
            Vt[d * 72 + (skey ^ ((d >> 3) << 3))] = vs[j];
        }
        __syncthreads();
        floatx4 sfr[4];
#pragma unroll
        for (int fn = 0; fn < 4; fn++) {
            short8 kf = *(const short8*)&Kt[(fn * 16 + l16) * 40 + quad * 8];
            sfr[fn] = __builtin_amdgcn_mfma_f32_16x16x32_bf16(
                qfrag, kf, (floatx4){0.f,0.f,0.f,0.f}, 0, 0, 0);
        }
#pragma unroll
        for (int fn = 0; fn < 4; fn++) {
            const int keyl = fn * 16 + l16;
            const float pv = padf[t * 64 + keyl];
#pragma unroll
            for (int r = 0; r < 4; r++) {
                float p = (pv != 0.f) ? 0.f : __expf(sfr[fn][r] * scale);
                ushort_t pb = bf16r(p);
                lsum[r] += bf2f(pb);
                Ps[(q0 + quad * 4 + r) * 72 + keyl] = pb;
            }
        }
#pragma unroll
        for (int kc = 0; kc < 2; kc++) {
            short8 pf = *(const short8*)&Ps[(q0 + l16) * 72 + kc * 32 + quad * 8];
            {
                const int d = l16;
                short8 vf = *(const short8*)&Vt[d * 72 + ((kc * 32 + quad * 8) ^ ((d >> 3) << 3))];
                o0 = __builtin_amdgcn_mfma_f32_16x16x32_bf16(pf, vf, o0, 0, 0, 0);
            }
            {
                const int d = 16 + l16;
                short8 vf = *(const short8*)&Vt[d * 72 + ((kc * 32 + quad * 8) ^ ((d >> 3) << 3))];
                o1 = __builtin_amdgcn_mfma_f32_16x16x32_bf16(pf, vf, o1, 0, 0, 0);
            }
        }
    }
#pragma unroll
    for (int r = 0; r < 4; r++) {
        float v = lsum[r];
        v += __shfl_xor(v, 1); v += __shfl_xor(v, 2);
        v += __shfl_xor(v, 4); v += __shfl_xor(v, 8);
        lsum[r] = 1.f / v;
    }
    const int nq = b * SEQ + qt * 64 + q0 + quad * 4;
#pragma unroll
    for (int r = 0; r < 4; r++) {
        ushort_t* outp = ctxb + (size_t)(nq + r) * 256 + hh * 32;
        outp[l16]      = bf16r(o0[r] * lsum[r]);
        outp[16 + l16] = bf16r(o1[r] * lsum[r]);
    }
}

// ---------------------------------------------------------------------------
// Residual add + LayerNorm (in place into h, plus bf16 copy hb).
// ---------------------------------------------------------------------------
__global__ __launch_bounds__(256) void add_ln(
    float* __restrict__ h, const float* __restrict__ add,
    const float* __restrict__ g, const float* __restrict__ b,
    ushort_t* __restrict__ hb)
{
    __shared__ float wred[8];
    const int n = blockIdx.x;
    const int d = threadIdx.x;
    const int wave = d >> 6;
    const float v = h[n * D_MODEL + d] + add[n * D_MODEL + d];
    float s = v;
    for (int o = 1; o < 64; o <<= 1) s += __shfl_xor(s, o);
    if ((d & 63) == 0) wred[wave] = s;
    __syncthreads();
    const float mu = (wred[0] + wred[1] + wred[2] + wred[3]) * (1.0f / 256.0f);
    const float c = v - mu;
    float cs = c * c;
    for (int o = 1; o < 64; o <<= 1) cs += __shfl_xor(cs, o);
    if ((d & 63) == 0) wred[4 + wave] = cs;
    __syncthreads();
    const float var = (wred[4] + wred[5] + wred[6] + wred[7]) * (1.0f / 256.0f);
    const float o = c * rsqrtf(var + 1e-5f) * g[d] + b[d];
    h[n * D_MODEL + d] = o;
    hb[n * D_MODEL + d] = bf16r(o);
}

// ---------------------------------------------------------------------------
// Gate v2: 128 tokens/block (64 blocks), wave computes 32 tokens; block-level
// LDS histogram -> 8 padded global atomics/block. fp32 routing, same
// tie-break as jnp.argmax.
// ---------------------------------------------------------------------------
__global__ __launch_bounds__(256) void gate_kernel(
    const float* __restrict__ h, const float* __restrict__ gw,
    const float* __restrict__ gb, int* __restrict__ top_idx,
    float* __restrict__ top_w, int* __restrict__ pos, int* __restrict__ counts)
{
    __shared__ int lidx[128];
    __shared__ int lpos[128];
    __shared__ int hist[NE];
    __shared__ int base[NE];
    const int wave = threadIdx.x >> 6;
    const int lane = threadIdx.x & 63;
    const int t0 = blockIdx.x * 128 + wave * 32;
    // preload gate weights: lane covers d = lane*4 .. lane*4+3
    float4 gwr[NE];
#pragma unroll
    for (int e = 0; e < NE; e++)
        gwr[e] = *(const float4*)&gw[e * D_MODEL + lane * 4];
    float gbr[NE];
#pragma unroll
    for (int e = 0; e < NE; e++) gbr[e] = gb[e];

    for (int i = 0; i < 32; i++) {
        const int n = t0 + i;
        float4 hv = *(const float4*)&h[(size_t)n * D_MODEL + lane * 4];
        float lg[NE];
#pragma unroll
        for (int e = 0; e < NE; e++)
            lg[e] = hv.x * gwr[e].x + hv.y * gwr[e].y + hv.z * gwr[e].z + hv.w * gwr[e].w;
#pragma unroll
        for (int e = 0; e < NE; e++) {
            float v = lg[e];
            for (int o = 1; o < 64; o <<= 1) v += __shfl_xor(v, o);
            lg[e] = v;
        }
        if (lane == 0) {
            float best = -1e30f; int bi = 0;
#pragma unroll
            for (int e = 0; e < NE; e++) {
                lg[e] += gbr[e];
                if (lg[e] > best) { best = lg[e]; bi = e; }
            }
            float ssum = 0.0f;
#pragma unroll
            for (int e = 0; e < NE; e++) ssum += __expf(lg[e] - best);
            top_idx[n] = bi;
            top_w[n] = 1.0f / ssum;
            lidx[wave * 32 + i] = bi;
        }
    }
    __syncthreads();
    if (threadIdx.x < NE) hist[threadIdx.x] = 0;
    __syncthreads();
    if (threadIdx.x < 128)
        lpos[threadIdx.x] = atomicAdd(&hist[lidx[threadIdx.x]], 1);
    __syncthreads();
    if (threadIdx.x < NE)
        base[threadIdx.x] = atomicAdd(&counts[threadIdx.x * CSTRIDE], hist[threadIdx.x]);
    __syncthreads();
    if (threadIdx.x < 128)
        pos[blockIdx.x * 128 + threadIdx.x] = base[lidx[threadIdx.x]] + lpos[threadIdx.x];
}

__global__ __launch_bounds__(256) void scatter_perm(
    const int* __restrict__ top_idx, const int* __restrict__ pos,
    const int* __restrict__ counts, int* __restrict__ perm)
{
    __shared__ int offs_s[NE];
    if (threadIdx.x < NE) {
        int a = 0;
        for (int i = 0; i < (int)threadIdx.x; i++) a += counts[i * CSTRIDE];
        offs_s[threadIdx.x] = a;
    }
    __syncthreads();
    const int n = blockIdx.x * 256 + threadIdx.x;
    if (n < NTOK) perm[offs_s[top_idx[n]] + pos[n]] = n;
}

// ---------------------------------------------------------------------------
// Masked mean pool, stage 1: 16x16 blocks, partial sums via atomics.
// ---------------------------------------------------------------------------
__global__ __launch_bounds__(256) void pool1(
    const float* __restrict__ h, const int* __restrict__ pad,
    float* __restrict__ pooled, float* __restrict__ cntb)
{
    const int b = blockIdx.x, c = blockIdx.y, d = threadIdx.x;
    float s = 0.0f; int cnt = 0;
    for (int i = 0; i < 32; i++) {
        const int idx = b * SEQ + c * 32 + i;
        if (!pad[idx]) { s += h[(size_t)idx * D_MODEL + d]; cnt++; }
    }
    atomicAdd(&pooled[b * D_MODEL + d], s);
    if (d == 0) atomicAdd(&cntb[b], (float)cnt);
}

__global__ __launch_bounds__(128) void cls_kernel(
    const float* __restrict__ pooled, const float* __restrict__ cntb,
    const float* __restrict__ fc1w, const float* __restrict__ fc1b,
    const float* __restrict__ fc2w, const float* __restrict__ fc2b,
    float* __restrict__ out)
{
    __shared__ float zs[128];
    const int b = blockIdx.x;
    const int j = threadIdx.x;
    const float invc = 1.0f / fmaxf(cntb[b], 1.0f);
    float s = 0.0f;
    for (int d = 0; d < D_MODEL; d++) s += pooled[b * D_MODEL + d] * fc1w[j * D_MODEL + d];
    zs[j] = fmaxf(s * invc + fc1b[j], 0.0f);
    __syncthreads();
    if (j < 2) {
        float o = fc2b[j];
        for (int i = 0; i < 128; i++) o += zs[i] * fc2w[j * 128 + i];
        out[b * 2 + j] = o;
    }
}

// ---------------------------------------------------------------------------
extern "C" void kernel_launch(void* const* d_in, const int* in_sizes, int n_in,
                              void* d_out, int out_size, void* d_ws, size_t ws_size,
                              hipStream_t stream)
{
    const int*   x          = (const int*)d_in[0];
    const float* emb        = (const float*)d_in[1];
    const float* in_proj_w  = (const float*)d_in[2];
    const float* in_proj_b  = (const float*)d_in[3];
    const float* out_proj_w = (const float*)d_in[4];
    const float* out_proj_b = (const float*)d_in[5];
    const float* ln1_g      = (const float*)d_in[6];
    const float* ln1_b      = (const float*)d_in[7];
    const float* ln2_g      = (const float*)d_in[8];
    const float* ln2_b      = (const float*)d_in[9];
    const float* gate_w     = (const float*)d_in[10];
    const float* gate_b     = (const float*)d_in[11];
    const float* w1         = (const float*)d_in[12];
    const float* b1         = (const float*)d_in[13];
    const float* w2         = (const float*)d_in[14];
    const float* b2         = (const float*)d_in[15];
    const float* fc1_w      = (const float*)d_in[16];
    const float* fc1_b      = (const float*)d_in[17];
    const float* fc2_w      = (const float*)d_in[18];
    const float* fc2_b      = (const float*)d_in[19];
    float* out = (float*)d_out;

    // workspace layout (float slots)
    float* ws = (float*)d_ws;
    float*    h      = ws;                          // 2,097,152 f
    float*    tmp    = ws + 2097152;                // 2,097,152 f
    ushort_t* qkvb   = (ushort_t*)(ws + 4194304);   // 8192*768 bf16
    ushort_t* ctxb   = (ushort_t*)(ws + 7340032);   // 8192*256 bf16
    ushort_t* ehb    = (ushort_t*)(ws + 4194304);   // 8192*1024 bf16 aliases qkvb+ctxb
    ushort_t* hb     = (ushort_t*)(ws + 8388608);   // 8192*256 bf16
    ushort_t* wb     = (ushort_t*)(ws + 9437184);   // up to 2,097,152 bf16
    float*    top_w  = ws + 10485760;               // 8192
    float*    pooled = ws + 10493952;               // 4096
    float*    cntb   = ws + 10498048;               // 16
    int* ipart   = (int*)(ws + 10498064);
    int* pad     = ipart;              // 8192
    int* top_idx = ipart + 8192;
    int* pos     = ipart + 16384;
    int* perm    = ipart + 24576;
    int* counts  = ipart + 32768;      // NE*CSTRIDE

    embed_kernel<<<NTOK, 256, 0, stream>>>(x, emb, h, hb, pad);
    hipMemsetAsync(pooled, 0, (NB * D_MODEL + NB) * sizeof(float), stream);

    for (int l = 0; l < 2; l++) {
        // --- qkv projection (bf16 MFMA) ---
        wconv<<<192, 256, 0, stream>>>(in_proj_w + (size_t)l * 196608, wb, 196608);
        mfma_gemm<<<dim3(768 / 64, NTOK / 64, 1), 256, 0, stream>>>(
            hb, wb, in_proj_b + l * 768, qkvb, NTOK, 768, 256,
            nullptr, nullptr, nullptr, GF_OUTBF16);
        // --- attention (MFMA flash) -> ctxb ---
        attn_kernel<<<NB * NH * (SEQ / 64), 256, 0, stream>>>(qkvb, pad, ctxb);
        // --- output projection -> tmp (fp32) ---
        wconv<<<64, 256, 0, stream>>>(out_proj_w + (size_t)l * 65536, wb, 65536);
        mfma_gemm<<<dim3(256 / 64, NTOK / 64, 1), 256, 0, stream>>>(
            ctxb, wb, out_proj_b + l * 256, tmp, NTOK, 256, 256,
            nullptr, nullptr, nullptr, 0);
        add_ln<<<NTOK, 256, 0, stream>>>(h, tmp, ln1_g + l * 256, ln1_b + l * 256, hb);
        // --- MoE routing (fp32, block-aggregated atomics) ---
        hipMemsetAsync(counts, 0, NE * CSTRIDE * sizeof(int), stream);
        gate_kernel<<<NTOK / 128, 256, 0, stream>>>(
            h, gate_w + l * NE * 256, gate_b + l * NE, top_idx, top_w, pos, counts);
        scatter_perm<<<NTOK / 256, 256, 0, stream>>>(top_idx, pos, counts, perm);
        // --- MoE expert GEMMs (routed expert only, bf16 MFMA) ---
        wconv<<<2048, 256, 0, stream>>>(w1 + (size_t)l * 2097152, wb, 2097152);
        mfma_gemm<<<dim3(EHID / 64, NTOK / 64, NE), 256, 0, stream>>>(
            hb, wb, b1 + l * NE * EHID, ehb, 0, EHID, 256,
            counts, perm, nullptr, GF_GATHER | GF_RELU | GF_OUTBF16);
        wconv<<<2048, 256, 0, stream>>>(w2 + (size_t)l * 2097152, wb, 2097152);
        mfma_gemm<<<dim3(D_MODEL / 64, NTOK / 64, NE), 256, 0, stream>>>(
            ehb, wb, b2 + l * NE * 256, tmp, 0, D_MODEL, 1024,
            counts, perm, top_w, GF_SCATTER);
        add_ln<<<NTOK, 256, 0, stream>>>(h, tmp, ln2_g + l * 256, ln2_b + l * 256, hb);
    }

    pool1<<<dim3(NB, 16), 256, 0, stream>>>(h, pad, pooled, cntb);
    cls_kernel<<<NB, 128, 0, stream>>>(pooled, cntb, fc1_w, fc1_b, fc2_w, fc2_b, out);
}